// Round 2
// baseline (568.509 us; speedup 1.0000x reference)
//
#include <hip/hip_runtime.h>

typedef _Float16 half8 __attribute__((ext_vector_type(8)));
typedef float floatx4 __attribute__((ext_vector_type(4)));
typedef int intx4 __attribute__((ext_vector_type(4)));

#define MFMA16(a, b, c) __builtin_amdgcn_mfma_f32_16x16x32_f16(a, b, c, 0, 0, 0)

static constexpr int kC = 64, kH = 64, kW = 64;
static constexpr int kM = 512, kD = 576;  // D = C*9
// ws layout (f16 elements), hi/lo interleaved per k-octet (8 hi, 8 lo):
//   WS1 (GEMM1 B): [m:512][k8:72][16]   elem = m*1152 + k8*16 + (0..7 hi / 8..15 lo)
//   WS2 (GEMM2 B): [d:576][m8:64][16]   elem = WS2 + d*1024 + m8*16 + ...
static constexpr int WS2 = 589824;
// total ws: 1179648 f16 = 2,359,296 bytes

__global__ void prep_split(const float* __restrict__ mem, _Float16* __restrict__ ws) {
  const int m = blockIdx.x;   // 512
  const int d = threadIdx.x;  // 576
  float v = mem[m * kD + d];
  _Float16 hi = (_Float16)v;
  _Float16 lo = (_Float16)(v - (float)hi);
  ws[m * 1152 + ((d >> 3) << 4) + (d & 7)] = hi;
  ws[m * 1152 + ((d >> 3) << 4) + (d & 7) + 8] = lo;
  ws[WS2 + d * 1024 + ((m >> 3) << 4) + (m & 7)] = hi;
  ws[WS2 + d * 1024 + ((m >> 3) << 4) + (m & 7) + 8] = lo;
}

// One block: 32 pixels (b, h, w0..w0+31). 4 waves.
__global__ __launch_bounds__(256, 2) void mem_branch_kernel(
    const float* __restrict__ x, const float* __restrict__ temperature,
    const _Float16* __restrict__ ws, float* __restrict__ out) {
  // A fragments: [36 combos (kt*2+rt)][64 lanes][8 f16]; hi at 0, lo at +18432.
  // Later aliased by att fragments: [32 combos][64][8]; hi 0, lo +16384.
  __shared__ __align__(16) _Float16 afrag[36 * 64 * 8 * 2];
  __shared__ __align__(16) int tab[kD];
  __shared__ float red_max[4][32];
  __shared__ float red_sum[4][32];

  const int tid = threadIdx.x;
  const int lane = tid & 63;
  const int wv = tid >> 6;
  const int l15 = lane & 15;
  const int koct = lane >> 4;  // 0..3
  const int bx = blockIdx.x;
  const int b = bx >> 7;
  const int h = (bx >> 1) & 63;
  const int w0 = (bx & 1) << 5;

  const float sfac = temperature[0] * 0.060112293370373475f;  // (1/24)*log2(e)

  for (int d = tid; d < kD; d += 256) {
    int c = d / 9, r9 = d % 9, kh = r9 / 3, kw = r9 % 3;
    tab[d] = (c << 12) + (kh << 6) + kw + (kh << 20) + (kw << 24);
  }
  __syncthreads();

  // ---- build patch A-fragments (hi/lo f16) directly in fragment layout ----
  {
    const int base0 = ((b * kC) * kH + (h - 1)) * kW + (w0 - 1);
    for (int combo = wv; combo < 36; combo += 4) {
      const int kt = combo >> 1, rt = combo & 1;
      const int pp = rt * 16 + l15;  // pixel 0..31
      const int dbase = kt * 32 + koct * 8;
      intx4 t0 = *reinterpret_cast<const intx4*>(&tab[dbase]);
      intx4 t1 = *reinterpret_cast<const intx4*>(&tab[dbase + 4]);
      half8 hv, lv;
#pragma unroll
      for (int j = 0; j < 8; ++j) {
        int t = (j < 4) ? t0[j] : t1[j - 4];
        int off = t & 0xFFFFF;
        int kh = (t >> 20) & 15;
        int kw = (t >> 24) & 15;
        bool ok = ((unsigned)(h - 1 + kh) < 64u) && ((unsigned)(w0 + pp - 1 + kw) < 64u);
        int idx = ok ? (base0 + pp + off) : 0;
        float v = x[idx];
        v = ok ? v : 0.0f;
        _Float16 hi = (_Float16)v;
        hv[j] = hi;
        lv[j] = (_Float16)(v - (float)hi);
      }
      *reinterpret_cast<half8*>(&afrag[(combo * 64 + lane) * 8]) = hv;
      *reinterpret_cast<half8*>(&afrag[18432 + (combo * 64 + lane) * 8]) = lv;
    }
  }
  __syncthreads();

  // ---- GEMM1: wave owns m in [wv*128, wv*128+128), 8 m-tiles; full-kt B prefetch ----
  floatx4 acc[2][8];
  const floatx4 zed = {0.0f, 0.0f, 0.0f, 0.0f};
#pragma unroll
  for (int rt = 0; rt < 2; ++rt)
#pragma unroll
    for (int mt = 0; mt < 8; ++mt) acc[rt][mt] = zed;
  {
    const int mrow = wv * 128 + l15;
    const _Float16* bbase1[8];
#pragma unroll
    for (int mt = 0; mt < 8; ++mt) bbase1[mt] = ws + (mrow + mt * 16) * 1152 + koct * 16;
    half8 cbh[8], cbl[8];
#pragma unroll
    for (int mt = 0; mt < 8; ++mt) {
      cbh[mt] = *reinterpret_cast<const half8*>(bbase1[mt]);
      cbl[mt] = *reinterpret_cast<const half8*>(bbase1[mt] + 8);
    }
#pragma unroll
    for (int kt = 0; kt < 18; ++kt) {
      half8 ah0 = *reinterpret_cast<const half8*>(&afrag[((kt * 2 + 0) * 64 + lane) * 8]);
      half8 ah1 = *reinterpret_cast<const half8*>(&afrag[((kt * 2 + 1) * 64 + lane) * 8]);
      half8 al0 = *reinterpret_cast<const half8*>(&afrag[18432 + ((kt * 2 + 0) * 64 + lane) * 8]);
      half8 al1 = *reinterpret_cast<const half8*>(&afrag[18432 + ((kt * 2 + 1) * 64 + lane) * 8]);
      half8 nbh[8], nbl[8];
      if (kt < 17) {
#pragma unroll
        for (int mt = 0; mt < 8; ++mt) {
          nbh[mt] = *reinterpret_cast<const half8*>(bbase1[mt] + (kt + 1) * 64);
          nbl[mt] = *reinterpret_cast<const half8*>(bbase1[mt] + (kt + 1) * 64 + 8);
        }
      }
      __builtin_amdgcn_s_setprio(1);
#pragma unroll
      for (int mt = 0; mt < 8; ++mt) {
        acc[0][mt] = MFMA16(ah0, cbh[mt], acc[0][mt]);
        acc[1][mt] = MFMA16(ah1, cbh[mt], acc[1][mt]);
        acc[0][mt] = MFMA16(ah0, cbl[mt], acc[0][mt]);
        acc[1][mt] = MFMA16(ah1, cbl[mt], acc[1][mt]);
        acc[0][mt] = MFMA16(al0, cbh[mt], acc[0][mt]);
        acc[1][mt] = MFMA16(al1, cbh[mt], acc[1][mt]);
      }
      __builtin_amdgcn_s_setprio(0);
      if (kt < 17) {
#pragma unroll
        for (int mt = 0; mt < 8; ++mt) {
          cbh[mt] = nbh[mt];
          cbl[mt] = nbl[mt];
        }
      }
    }
  }

  // ---- softmax over m (512); lane: p = rt*16+koct*4+r, m = wv*128+mt*16+l15 ----
  float pm[2][4], ps[2][4], gm[2][4], rinv[2][4];
#pragma unroll
  for (int rt = 0; rt < 2; ++rt)
#pragma unroll
    for (int r = 0; r < 4; ++r) {
      float v = acc[rt][0][r];
#pragma unroll
      for (int mt = 1; mt < 8; ++mt) v = fmaxf(v, acc[rt][mt][r]);
      pm[rt][r] = v;
    }
#pragma unroll
  for (int off = 1; off < 16; off <<= 1)
#pragma unroll
    for (int rt = 0; rt < 2; ++rt)
#pragma unroll
      for (int r = 0; r < 4; ++r) pm[rt][r] = fmaxf(pm[rt][r], __shfl_xor(pm[rt][r], off, 64));
  if (l15 == 0) {
#pragma unroll
    for (int rt = 0; rt < 2; ++rt)
#pragma unroll
      for (int r = 0; r < 4; ++r) red_max[wv][rt * 16 + koct * 4 + r] = pm[rt][r];
  }
  __syncthreads();
#pragma unroll
  for (int rt = 0; rt < 2; ++rt)
#pragma unroll
    for (int r = 0; r < 4; ++r) {
      int p = rt * 16 + koct * 4 + r;
      gm[rt][r] = fmaxf(fmaxf(red_max[0][p], red_max[1][p]), fmaxf(red_max[2][p], red_max[3][p]));
      ps[rt][r] = 0.0f;
    }
#pragma unroll
  for (int rt = 0; rt < 2; ++rt)
#pragma unroll
    for (int mt = 0; mt < 8; ++mt)
#pragma unroll
      for (int r = 0; r < 4; ++r) {
        float e = exp2f((acc[rt][mt][r] - gm[rt][r]) * sfac);
        acc[rt][mt][r] = e;
        ps[rt][r] += e;
      }
#pragma unroll
  for (int off = 1; off < 16; off <<= 1)
#pragma unroll
    for (int rt = 0; rt < 2; ++rt)
#pragma unroll
      for (int r = 0; r < 4; ++r) ps[rt][r] += __shfl_xor(ps[rt][r], off, 64);
  if (l15 == 0) {
#pragma unroll
    for (int rt = 0; rt < 2; ++rt)
#pragma unroll
      for (int r = 0; r < 4; ++r) red_sum[wv][rt * 16 + koct * 4 + r] = ps[rt][r];
  }
  __syncthreads();
#pragma unroll
  for (int rt = 0; rt < 2; ++rt)
#pragma unroll
    for (int r = 0; r < 4; ++r) {
      int p = rt * 16 + koct * 4 + r;
      rinv[rt][r] = 1.0f / (red_sum[0][p] + red_sum[1][p] + red_sum[2][p] + red_sum[3][p]);
    }
  // write att hi/lo fragments into (aliased) afrag
#pragma unroll
  for (int rt = 0; rt < 2; ++rt)
#pragma unroll
    for (int mt = 0; mt < 8; ++mt)
#pragma unroll
      for (int r = 0; r < 4; ++r) {
        float a = acc[rt][mt][r] * rinv[rt][r];
        _Float16 hi = (_Float16)a;
        _Float16 lo = (_Float16)(a - (float)hi);
        int m = wv * 128 + mt * 16 + l15;
        int lf = (koct * 4 + r) + (((m >> 3) & 3) << 4);
        int idxe = ((((m >> 5) << 1) + rt) * 64 + lf) * 8 + (m & 7);
        afrag[idxe] = hi;
        afrag[16384 + idxe] = lo;
      }
  __syncthreads();

  // ---- GEMM2: out[32][576] = att @ memory; wave owns d in [wv*144, +144) ----
  // B prefetched one full kt2 ahead, issued in two sub-groups (5 nt + 4 nt).
  floatx4 acc2[2][9];
#pragma unroll
  for (int rt = 0; rt < 2; ++rt)
#pragma unroll
    for (int nt = 0; nt < 9; ++nt) acc2[rt][nt] = zed;
  {
    const int d0 = wv * 144 + l15;
    const _Float16* bbase2[9];
#pragma unroll
    for (int nt = 0; nt < 9; ++nt) bbase2[nt] = ws + WS2 + (d0 + nt * 16) * 1024 + koct * 16;
    half8 c0h[5], c0l[5], c1h[4], c1l[4];
#pragma unroll
    for (int g = 0; g < 5; ++g) {
      c0h[g] = *reinterpret_cast<const half8*>(bbase2[g]);
      c0l[g] = *reinterpret_cast<const half8*>(bbase2[g] + 8);
    }
#pragma unroll
    for (int g = 0; g < 4; ++g) {
      c1h[g] = *reinterpret_cast<const half8*>(bbase2[5 + g]);
      c1l[g] = *reinterpret_cast<const half8*>(bbase2[5 + g] + 8);
    }
#pragma unroll
    for (int kt2 = 0; kt2 < 16; ++kt2) {
      half8 a2h0 = *reinterpret_cast<const half8*>(&afrag[((kt2 * 2 + 0) * 64 + lane) * 8]);
      half8 a2h1 = *reinterpret_cast<const half8*>(&afrag[((kt2 * 2 + 1) * 64 + lane) * 8]);
      half8 a2l0 = *reinterpret_cast<const half8*>(&afrag[16384 + ((kt2 * 2 + 0) * 64 + lane) * 8]);
      half8 a2l1 = *reinterpret_cast<const half8*>(&afrag[16384 + ((kt2 * 2 + 1) * 64 + lane) * 8]);
      half8 n0h[5], n0l[5], n1h[4], n1l[4];
      if (kt2 < 15) {
#pragma unroll
        for (int g = 0; g < 5; ++g) {
          n0h[g] = *reinterpret_cast<const half8*>(bbase2[g] + (kt2 + 1) * 64);
          n0l[g] = *reinterpret_cast<const half8*>(bbase2[g] + (kt2 + 1) * 64 + 8);
        }
      }
      __builtin_amdgcn_s_setprio(1);
#pragma unroll
      for (int g = 0; g < 5; ++g) {
        acc2[0][g] = MFMA16(a2h0, c0h[g], acc2[0][g]);
        acc2[1][g] = MFMA16(a2h1, c0h[g], acc2[1][g]);
        acc2[0][g] = MFMA16(a2h0, c0l[g], acc2[0][g]);
        acc2[1][g] = MFMA16(a2h1, c0l[g], acc2[1][g]);
        acc2[0][g] = MFMA16(a2l0, c0h[g], acc2[0][g]);
        acc2[1][g] = MFMA16(a2l1, c0h[g], acc2[1][g]);
      }
      __builtin_amdgcn_s_setprio(0);
      if (kt2 < 15) {
#pragma unroll
        for (int g = 0; g < 4; ++g) {
          n1h[g] = *reinterpret_cast<const half8*>(bbase2[5 + g] + (kt2 + 1) * 64);
          n1l[g] = *reinterpret_cast<const half8*>(bbase2[5 + g] + (kt2 + 1) * 64 + 8);
        }
      }
      __builtin_amdgcn_s_setprio(1);
#pragma unroll
      for (int g = 0; g < 4; ++g) {
        acc2[0][5 + g] = MFMA16(a2h0, c1h[g], acc2[0][5 + g]);
        acc2[1][5 + g] = MFMA16(a2h1, c1h[g], acc2[1][5 + g]);
        acc2[0][5 + g] = MFMA16(a2h0, c1l[g], acc2[0][5 + g]);
        acc2[1][5 + g] = MFMA16(a2h1, c1l[g], acc2[1][5 + g]);
        acc2[0][5 + g] = MFMA16(a2l0, c1h[g], acc2[0][5 + g]);
        acc2[1][5 + g] = MFMA16(a2l1, c1h[g], acc2[1][5 + g]);
      }
      __builtin_amdgcn_s_setprio(0);
      if (kt2 < 15) {
#pragma unroll
        for (int g = 0; g < 5; ++g) {
          c0h[g] = n0h[g];
          c0l[g] = n0l[g];
        }
#pragma unroll
        for (int g = 0; g < 4; ++g) {
          c1h[g] = n1h[g];
          c1l[g] = n1l[g];
        }
      }
    }
  }
  // ---- epilogue ----
  {
    const int nbase = b * 4096 + h * 64 + w0;
#pragma unroll
    for (int rt = 0; rt < 2; ++rt)
#pragma unroll
      for (int nt = 0; nt < 9; ++nt)
#pragma unroll
        for (int r = 0; r < 4; ++r) {
          int p = rt * 16 + koct * 4 + r;
          int d = wv * 144 + l15 + nt * 16;
          out[(nbase + p) * 576 + d] = acc2[rt][nt][r];
        }
  }
}

extern "C" void kernel_launch(void* const* d_in, const int* in_sizes, int n_in,
                              void* d_out, int out_size, void* d_ws, size_t ws_size,
                              hipStream_t stream) {
  const float* x = (const float*)d_in[0];
  const float* memory = (const float*)d_in[1];
  const float* temperature = (const float*)d_in[2];
  float* out = (float*)d_out;
  _Float16* ws = (_Float16*)d_ws;  // needs 2,359,296 bytes

  prep_split<<<512, 576, 0, stream>>>(memory, ws);
  mem_branch_kernel<<<2048, 256, 0, stream>>>(x, temperature, ws, out);
}

// Round 3
// 563.726 us; speedup vs baseline: 1.0085x; 1.0085x over previous
//
#include <hip/hip_runtime.h>

typedef _Float16 half8 __attribute__((ext_vector_type(8)));
typedef float floatx4 __attribute__((ext_vector_type(4)));
typedef int intx4 __attribute__((ext_vector_type(4)));

#define MFMA16(a, b, c) __builtin_amdgcn_mfma_f32_16x16x32_f16(a, b, c, 0, 0, 0)

static __device__ __forceinline__ half8 asH8(intx4 v) {
  half8 r;
  __builtin_memcpy(&r, &v, 16);
  return r;
}

static constexpr int kC = 64, kH = 64, kW = 64;
static constexpr int kM = 512, kD = 576;  // D = C*9
// ws layout (f16 elements), hi/lo interleaved per k-octet (8 hi, 8 lo):
//   WS1 (GEMM1 B): [m:512][k8:72][16]   elem = m*1152 + k8*16 + (0..7 hi / 8..15 lo)
//   WS2 (GEMM2 B): [d:576][m8:64][16]   elem = WS2 + d*1024 + m8*16 + ...
static constexpr int WS2 = 589824;
// total ws: 1179648 f16 = 2,359,296 bytes

__global__ void prep_split(const float* __restrict__ mem, _Float16* __restrict__ ws) {
  const int m = blockIdx.x;   // 512
  const int d = threadIdx.x;  // 576
  float v = mem[m * kD + d];
  _Float16 hi = (_Float16)v;
  _Float16 lo = (_Float16)(v - (float)hi);
  ws[m * 1152 + ((d >> 3) << 4) + (d & 7)] = hi;
  ws[m * 1152 + ((d >> 3) << 4) + (d & 7) + 8] = lo;
  ws[WS2 + d * 1024 + ((m >> 3) << 4) + (m & 7)] = hi;
  ws[WS2 + d * 1024 + ((m >> 3) << 4) + (m & 7) + 8] = lo;
}

// One block: 32 pixels (b, h, w0..w0+31). 4 waves.
__global__ __launch_bounds__(256, 2) void mem_branch_kernel(
    const float* __restrict__ x, const float* __restrict__ temperature,
    const _Float16* __restrict__ ws, float* __restrict__ out) {
  __shared__ __align__(16) _Float16 afrag[36 * 64 * 8 * 2];
  __shared__ __align__(16) int tab[kD];
  __shared__ float red_max[4][32];
  __shared__ float red_sum[4][32];

  const int tid = threadIdx.x;
  const int lane = tid & 63;
  const int wv = tid >> 6;
  const int l15 = lane & 15;
  const int koct = lane >> 4;  // 0..3
  const int bx = blockIdx.x;
  const int b = bx >> 7;
  const int h = (bx >> 1) & 63;
  const int w0 = (bx & 1) << 5;

  const float sfac = temperature[0] * 0.060112293370373475f;  // (1/24)*log2(e)
  const _Float16* wsp = ws;

  for (int d = tid; d < kD; d += 256) {
    int c = d / 9, r9 = d % 9, kh = r9 / 3, kw = r9 % 3;
    tab[d] = (c << 12) + (kh << 6) + kw + (kh << 20) + (kw << 24);
  }
  __syncthreads();

  // ---- build patch A-fragments (hi/lo f16) directly in fragment layout ----
  {
    const int base0 = ((b * kC) * kH + (h - 1)) * kW + (w0 - 1);
    for (int combo = wv; combo < 36; combo += 4) {
      const int kt = combo >> 1, rt = combo & 1;
      const int pp = rt * 16 + l15;  // pixel 0..31
      const int dbase = kt * 32 + koct * 8;
      intx4 t0 = *reinterpret_cast<const intx4*>(&tab[dbase]);
      intx4 t1 = *reinterpret_cast<const intx4*>(&tab[dbase + 4]);
      half8 hv, lv;
#pragma unroll
      for (int j = 0; j < 8; ++j) {
        int t = (j < 4) ? t0[j] : t1[j - 4];
        int off = t & 0xFFFFF;
        int kh = (t >> 20) & 15;
        int kw = (t >> 24) & 15;
        bool ok = ((unsigned)(h - 1 + kh) < 64u) && ((unsigned)(w0 + pp - 1 + kw) < 64u);
        int idx = ok ? (base0 + pp + off) : 0;
        float v = x[idx];
        v = ok ? v : 0.0f;
        _Float16 hi = (_Float16)v;
        hv[j] = hi;
        lv[j] = (_Float16)(v - (float)hi);
      }
      *reinterpret_cast<half8*>(&afrag[(combo * 64 + lane) * 8]) = hv;
      *reinterpret_cast<half8*>(&afrag[18432 + (combo * 64 + lane) * 8]) = lv;
    }
  }
  __syncthreads();

// ---- asm helpers: loads are invisible to the compiler; waits are manual ----
#define GLD16(dst, voff) \
  asm volatile("global_load_dwordx4 %0, %1, %2 offset:0" : "=v"(dst) : "v"(voff), "s"(wsp))
#define GLD16O(dst, voff) \
  asm volatile("global_load_dwordx4 %0, %1, %2 offset:16" : "=v"(dst) : "v"(voff), "s"(wsp))
#define VMW(N)                                             \
  do {                                                     \
    asm volatile("s_waitcnt vmcnt(" #N ")" ::: "memory");  \
    __builtin_amdgcn_sched_barrier(0);                     \
  } while (0)

  // ---- GEMM1: wave owns m in [wv*128, +128), 8 m-tiles; ring-3 pipelined B ----
  floatx4 acc[2][8];
  const floatx4 zed = {0.0f, 0.0f, 0.0f, 0.0f};
#pragma unroll
  for (int rt = 0; rt < 2; ++rt)
#pragma unroll
    for (int mt = 0; mt < 8; ++mt) acc[rt][mt] = zed;
  {
    const int mrow = wv * 128 + l15;
    int voffA[8];
#pragma unroll
    for (int mt = 0; mt < 8; ++mt) voffA[mt] = ((mrow + mt * 16) * 1152 + koct * 16) * 2;
    intx4 B1[3][8];  // [ring buf][mt_in_group*2 + hi/lo]
    half8 a0h, a1h, a0l, a1l;

#define G1_AREAD(KT)                                                       \
  do {                                                                     \
    a0h = *reinterpret_cast<const half8*>(&afrag[(((KT)*2 + 0) * 64 + lane) * 8]);        \
    a1h = *reinterpret_cast<const half8*>(&afrag[(((KT)*2 + 1) * 64 + lane) * 8]);        \
    a0l = *reinterpret_cast<const half8*>(&afrag[18432 + (((KT)*2 + 0) * 64 + lane) * 8]); \
    a1l = *reinterpret_cast<const half8*>(&afrag[18432 + (((KT)*2 + 1) * 64 + lane) * 8]); \
  } while (0)

#define G1_LOAD(B, G)                          \
  do {                                         \
    _Pragma("unroll") for (int q = 0; q < 4; ++q) { \
      int mt_ = (G)*4 + q;                     \
      GLD16(B1[B][q * 2], voffA[mt_]);         \
      GLD16O(B1[B][q * 2 + 1], voffA[mt_]);    \
      voffA[mt_] += 128;                       \
    }                                          \
  } while (0)

#define G1_MFMA(B, G)                                                 \
  do {                                                                \
    __builtin_amdgcn_s_setprio(1);                                    \
    _Pragma("unroll") for (int q = 0; q < 4; ++q) {                   \
      int mt_ = (G)*4 + q;                                            \
      acc[0][mt_] = MFMA16(a0h, asH8(B1[B][q * 2]), acc[0][mt_]);     \
      acc[1][mt_] = MFMA16(a1h, asH8(B1[B][q * 2]), acc[1][mt_]);     \
      acc[0][mt_] = MFMA16(a0h, asH8(B1[B][q * 2 + 1]), acc[0][mt_]); \
      acc[1][mt_] = MFMA16(a1h, asH8(B1[B][q * 2 + 1]), acc[1][mt_]); \
      acc[0][mt_] = MFMA16(a0l, asH8(B1[B][q * 2]), acc[0][mt_]);     \
      acc[1][mt_] = MFMA16(a1l, asH8(B1[B][q * 2]), acc[1][mt_]);     \
    }                                                                 \
    __builtin_amdgcn_s_setprio(0);                                    \
  } while (0)

    // prologue: issue (kt0,g0)->buf0, (kt0,g1)->buf1
    G1_LOAD(0, 0);
    G1_LOAD(1, 1);
    for (int m = 0; m < 5; ++m) {  // kt = 3m..3m+2 (0..14), issues up to kt=15
      G1_AREAD(3 * m);
      G1_LOAD(2, 0); VMW(16); G1_MFMA(0, 0);
      G1_LOAD(0, 1); VMW(16); G1_MFMA(1, 1);
      G1_AREAD(3 * m + 1);
      G1_LOAD(1, 0); VMW(16); G1_MFMA(2, 0);
      G1_LOAD(2, 1); VMW(16); G1_MFMA(0, 1);
      G1_AREAD(3 * m + 2);
      G1_LOAD(0, 0); VMW(16); G1_MFMA(1, 0);
      G1_LOAD(1, 1); VMW(16); G1_MFMA(2, 1);
    }
    // tail: kt = 15, 16, 17
    G1_AREAD(15);
    G1_LOAD(2, 0); VMW(16); G1_MFMA(0, 0);
    G1_LOAD(0, 1); VMW(16); G1_MFMA(1, 1);
    G1_AREAD(16);
    G1_LOAD(1, 0); VMW(16); G1_MFMA(2, 0);
    G1_LOAD(2, 1); VMW(16); G1_MFMA(0, 1);
    G1_AREAD(17);
    VMW(8);  G1_MFMA(1, 0);
    VMW(0);  G1_MFMA(2, 1);
  }

  // ---- softmax over m (512); lane: p = rt*16+koct*4+r, m = wv*128+mt*16+l15 ----
  float pm[2][4], ps[2][4], gm[2][4], rinv[2][4];
#pragma unroll
  for (int rt = 0; rt < 2; ++rt)
#pragma unroll
    for (int r = 0; r < 4; ++r) {
      float v = acc[rt][0][r];
#pragma unroll
      for (int mt = 1; mt < 8; ++mt) v = fmaxf(v, acc[rt][mt][r]);
      pm[rt][r] = v;
    }
#pragma unroll
  for (int off = 1; off < 16; off <<= 1)
#pragma unroll
    for (int rt = 0; rt < 2; ++rt)
#pragma unroll
      for (int r = 0; r < 4; ++r) pm[rt][r] = fmaxf(pm[rt][r], __shfl_xor(pm[rt][r], off, 64));
  if (l15 == 0) {
#pragma unroll
    for (int rt = 0; rt < 2; ++rt)
#pragma unroll
      for (int r = 0; r < 4; ++r) red_max[wv][rt * 16 + koct * 4 + r] = pm[rt][r];
  }
  __syncthreads();
#pragma unroll
  for (int rt = 0; rt < 2; ++rt)
#pragma unroll
    for (int r = 0; r < 4; ++r) {
      int p = rt * 16 + koct * 4 + r;
      gm[rt][r] = fmaxf(fmaxf(red_max[0][p], red_max[1][p]), fmaxf(red_max[2][p], red_max[3][p]));
      ps[rt][r] = 0.0f;
    }
#pragma unroll
  for (int rt = 0; rt < 2; ++rt)
#pragma unroll
    for (int mt = 0; mt < 8; ++mt)
#pragma unroll
      for (int r = 0; r < 4; ++r) {
        float e = exp2f((acc[rt][mt][r] - gm[rt][r]) * sfac);
        acc[rt][mt][r] = e;
        ps[rt][r] += e;
      }
#pragma unroll
  for (int off = 1; off < 16; off <<= 1)
#pragma unroll
    for (int rt = 0; rt < 2; ++rt)
#pragma unroll
      for (int r = 0; r < 4; ++r) ps[rt][r] += __shfl_xor(ps[rt][r], off, 64);
  if (l15 == 0) {
#pragma unroll
    for (int rt = 0; rt < 2; ++rt)
#pragma unroll
      for (int r = 0; r < 4; ++r) red_sum[wv][rt * 16 + koct * 4 + r] = ps[rt][r];
  }
  __syncthreads();
#pragma unroll
  for (int rt = 0; rt < 2; ++rt)
#pragma unroll
    for (int r = 0; r < 4; ++r) {
      int p = rt * 16 + koct * 4 + r;
      rinv[rt][r] = 1.0f / (red_sum[0][p] + red_sum[1][p] + red_sum[2][p] + red_sum[3][p]);
    }
  // write att hi/lo fragments into (aliased) afrag
#pragma unroll
  for (int rt = 0; rt < 2; ++rt)
#pragma unroll
    for (int mt = 0; mt < 8; ++mt)
#pragma unroll
      for (int r = 0; r < 4; ++r) {
        float a = acc[rt][mt][r] * rinv[rt][r];
        _Float16 hi = (_Float16)a;
        _Float16 lo = (_Float16)(a - (float)hi);
        int m = wv * 128 + mt * 16 + l15;
        int lf = (koct * 4 + r) + (((m >> 3) & 3) << 4);
        int idxe = ((((m >> 5) << 1) + rt) * 64 + lf) * 8 + (m & 7);
        afrag[idxe] = hi;
        afrag[16384 + idxe] = lo;
      }
  __syncthreads();

  // ---- GEMM2: out[32][576] = att @ memory; wave owns d in [wv*144, +144) ----
  floatx4 acc2[2][9];
#pragma unroll
  for (int rt = 0; rt < 2; ++rt)
#pragma unroll
    for (int nt = 0; nt < 9; ++nt) acc2[rt][nt] = zed;
  {
    const int d0 = wv * 144 + l15;
    int voffB[9];
#pragma unroll
    for (int nt = 0; nt < 9; ++nt) voffB[nt] = (WS2 + (d0 + nt * 16) * 1024 + koct * 16) * 2;
    intx4 B2[3][6];  // [ring buf][nt_in_group*2 + hi/lo]
    half8 a2h0, a2h1, a2l0, a2l1;

#define G2_AREAD(KT)                                                        \
  do {                                                                      \
    a2h0 = *reinterpret_cast<const half8*>(&afrag[(((KT)*2 + 0) * 64 + lane) * 8]);         \
    a2h1 = *reinterpret_cast<const half8*>(&afrag[(((KT)*2 + 1) * 64 + lane) * 8]);         \
    a2l0 = *reinterpret_cast<const half8*>(&afrag[16384 + (((KT)*2 + 0) * 64 + lane) * 8]); \
    a2l1 = *reinterpret_cast<const half8*>(&afrag[16384 + (((KT)*2 + 1) * 64 + lane) * 8]); \
  } while (0)

#define G2_LOAD(B, G)                          \
  do {                                         \
    _Pragma("unroll") for (int q = 0; q < 3; ++q) { \
      int nt_ = (G)*3 + q;                     \
      GLD16(B2[B][q * 2], voffB[nt_]);         \
      GLD16O(B2[B][q * 2 + 1], voffB[nt_]);    \
      voffB[nt_] += 128;                       \
    }                                          \
  } while (0)

#define G2_MFMA(B, G)                                                   \
  do {                                                                  \
    __builtin_amdgcn_s_setprio(1);                                      \
    _Pragma("unroll") for (int q = 0; q < 3; ++q) {                     \
      int nt_ = (G)*3 + q;                                              \
      acc2[0][nt_] = MFMA16(a2h0, asH8(B2[B][q * 2]), acc2[0][nt_]);    \
      acc2[1][nt_] = MFMA16(a2h1, asH8(B2[B][q * 2]), acc2[1][nt_]);    \
      acc2[0][nt_] = MFMA16(a2h0, asH8(B2[B][q * 2 + 1]), acc2[0][nt_]); \
      acc2[1][nt_] = MFMA16(a2h1, asH8(B2[B][q * 2 + 1]), acc2[1][nt_]); \
      acc2[0][nt_] = MFMA16(a2l0, asH8(B2[B][q * 2]), acc2[0][nt_]);    \
      acc2[1][nt_] = MFMA16(a2l1, asH8(B2[B][q * 2]), acc2[1][nt_]);    \
    }                                                                   \
    __builtin_amdgcn_s_setprio(0);                                      \
  } while (0)

    // prologue: (kt2=0,g0)->buf0, (0,g1)->buf1
    G2_LOAD(0, 0);
    G2_LOAD(1, 1);
    for (int kt2 = 0; kt2 < 15; ++kt2) {
      G2_AREAD(kt2);
      G2_LOAD(2, 2); VMW(12); G2_MFMA(0, 0);  // loads (kt2, g2)
      G2_LOAD(0, 0); VMW(12); G2_MFMA(1, 1);  // loads (kt2+1, g0)
      G2_LOAD(1, 1); VMW(12); G2_MFMA(2, 2);  // loads (kt2+1, g1)
    }
    // tail kt2 = 15
    G2_AREAD(15);
    G2_LOAD(2, 2); VMW(12); G2_MFMA(0, 0);
    VMW(6);  G2_MFMA(1, 1);
    VMW(0);  G2_MFMA(2, 2);
  }

  // ---- epilogue: nontemporal stores (don't evict ws from L2) ----
  {
    const int nbase = b * 4096 + h * 64 + w0;
#pragma unroll
    for (int rt = 0; rt < 2; ++rt)
#pragma unroll
      for (int nt = 0; nt < 9; ++nt)
#pragma unroll
        for (int r = 0; r < 4; ++r) {
          int p = rt * 16 + koct * 4 + r;
          int d = wv * 144 + l15 + nt * 16;
          __builtin_nontemporal_store(acc2[rt][nt][r], &out[(nbase + p) * 576 + d]);
        }
  }
}

extern "C" void kernel_launch(void* const* d_in, const int* in_sizes, int n_in,
                              void* d_out, int out_size, void* d_ws, size_t ws_size,
                              hipStream_t stream) {
  const float* x = (const float*)d_in[0];
  const float* memory = (const float*)d_in[1];
  const float* temperature = (const float*)d_in[2];
  float* out = (float*)d_out;
  _Float16* ws = (_Float16*)d_ws;  // needs 2,359,296 bytes

  prep_split<<<512, 576, 0, stream>>>(memory, ws);
  mem_branch_kernel<<<2048, 256, 0, stream>>>(x, temperature, ws, out);
}

// Round 4
// 427.600 us; speedup vs baseline: 1.3295x; 1.3183x over previous
//
#include <hip/hip_runtime.h>

typedef _Float16 half8 __attribute__((ext_vector_type(8)));
typedef float floatx4 __attribute__((ext_vector_type(4)));
typedef int intx4 __attribute__((ext_vector_type(4)));

#define MFMA16(a, b, c) __builtin_amdgcn_mfma_f32_16x16x32_f16(a, b, c, 0, 0, 0)

static __device__ __forceinline__ half8 asH8(intx4 v) {
  half8 r;
  __builtin_memcpy(&r, &v, 16);
  return r;
}

static constexpr int kC = 64, kH = 64, kW = 64;
static constexpr int kM = 512, kD = 576;  // D = C*9
// ws layout (f16 elements):
//   WS1 (GEMM1 B, hi/lo interleaved per k-octet): [m:512][k8:72][16]
//        elem = m*1152 + k8*16 + (0..7 hi / 8..15 lo)
//   WS2 (GEMM2 B, hi only): [d:576][m:512]  elem = WS2 + d*512 + m
static constexpr int WS2 = 589824;
// total ws: 884736 f16 = 1,769,472 bytes

__global__ void prep_split(const float* __restrict__ mem, _Float16* __restrict__ ws) {
  const int m = blockIdx.x;   // 512
  const int d = threadIdx.x;  // 576
  float v = mem[m * kD + d];
  _Float16 hi = (_Float16)v;
  _Float16 lo = (_Float16)(v - (float)hi);
  ws[m * 1152 + ((d >> 3) << 4) + (d & 7)] = hi;
  ws[m * 1152 + ((d >> 3) << 4) + (d & 7) + 8] = lo;
  ws[WS2 + d * 512 + m] = hi;
}

// One block: 32 pixels (b, h, w0..w0+31). 4 waves.
__global__ __launch_bounds__(256, 2) void mem_branch_kernel(
    const float* __restrict__ x, const float* __restrict__ temperature,
    const _Float16* __restrict__ ws, float* __restrict__ out) {
  // GEMM1 A fragments: [36 combos (kt*2+rt)][64 lanes][8 f16]; hi at 0, lo at +18432.
  // Later aliased by att-hi fragments: [32 combos (kt2*2+rt)][64][8] at base 0.
  __shared__ __align__(16) _Float16 afrag[36 * 64 * 8 * 2];
  __shared__ __align__(16) int tab[kD];
  __shared__ float red_max[4][32];
  __shared__ float red_sum[4][32];

  const int tid = threadIdx.x;
  const int lane = tid & 63;
  const int wv = tid >> 6;
  const int l15 = lane & 15;
  const int koct = lane >> 4;  // 0..3
  const int bx = blockIdx.x;
  const int b = bx >> 7;
  const int h = (bx >> 1) & 63;
  const int w0 = (bx & 1) << 5;

  const float sfac = temperature[0] * 0.060112293370373475f;  // (1/24)*log2(e)
  const _Float16* wsp = ws;

  for (int d = tid; d < kD; d += 256) {
    int c = d / 9, r9 = d % 9, kh = r9 / 3, kw = r9 % 3;
    tab[d] = (c << 12) + (kh << 6) + kw + (kh << 20) + (kw << 24);
  }
  __syncthreads();

  // ---- build patch A-fragments (hi/lo f16) directly in fragment layout ----
  {
    const int base0 = ((b * kC) * kH + (h - 1)) * kW + (w0 - 1);
    for (int combo = wv; combo < 36; combo += 4) {
      const int kt = combo >> 1, rt = combo & 1;
      const int pp = rt * 16 + l15;  // pixel 0..31
      const int dbase = kt * 32 + koct * 8;
      intx4 t0 = *reinterpret_cast<const intx4*>(&tab[dbase]);
      intx4 t1 = *reinterpret_cast<const intx4*>(&tab[dbase + 4]);
      half8 hv, lv;
#pragma unroll
      for (int j = 0; j < 8; ++j) {
        int t = (j < 4) ? t0[j] : t1[j - 4];
        int off = t & 0xFFFFF;
        int kh = (t >> 20) & 15;
        int kw = (t >> 24) & 15;
        bool ok = ((unsigned)(h - 1 + kh) < 64u) && ((unsigned)(w0 + pp - 1 + kw) < 64u);
        int idx = ok ? (base0 + pp + off) : 0;
        float v = x[idx];
        v = ok ? v : 0.0f;
        _Float16 hi = (_Float16)v;
        hv[j] = hi;
        lv[j] = (_Float16)(v - (float)hi);
      }
      *reinterpret_cast<half8*>(&afrag[(combo * 64 + lane) * 8]) = hv;
      *reinterpret_cast<half8*>(&afrag[18432 + (combo * 64 + lane) * 8]) = lv;
    }
  }
  __syncthreads();

// ---- asm helpers ----
#define GLD16(dst, voff) \
  asm volatile("global_load_dwordx4 %0, %1, %2 offset:0" : "=v"(dst) : "v"(voff), "s"(wsp))
#define GLD16O(dst, voff) \
  asm volatile("global_load_dwordx4 %0, %1, %2 offset:16" : "=v"(dst) : "v"(voff), "s"(wsp))
#define VMW(N)                                            \
  do {                                                    \
    asm volatile("s_waitcnt vmcnt(" #N ")" ::: "memory"); \
    __builtin_amdgcn_sched_barrier(0);                    \
  } while (0)

  // ---- GEMM1: wave owns m in [wv*128, +128); ring-4 of 2-mt groups, distance 3 ----
  floatx4 acc[2][8];
  const floatx4 zed = {0.0f, 0.0f, 0.0f, 0.0f};
#pragma unroll
  for (int rt = 0; rt < 2; ++rt)
#pragma unroll
    for (int mt = 0; mt < 8; ++mt) acc[rt][mt] = zed;
  {
    const int mrow = wv * 128 + l15;
    int voffA[8];
#pragma unroll
    for (int mt = 0; mt < 8; ++mt) voffA[mt] = (mrow + mt * 16) * 2304 + koct * 32;
    intx4 R00, R01, R02, R03, R10, R11, R12, R13;
    intx4 R20, R21, R22, R23, R30, R31, R32, R33;
    half8 ah0, ah1, al0, al1;

#define G1_AREAD(KT)                                                                       \
  do {                                                                                     \
    ah0 = *reinterpret_cast<const half8*>(&afrag[(((KT)*2 + 0) * 64 + lane) * 8]);         \
    ah1 = *reinterpret_cast<const half8*>(&afrag[(((KT)*2 + 1) * 64 + lane) * 8]);         \
    al0 = *reinterpret_cast<const half8*>(&afrag[18432 + (((KT)*2 + 0) * 64 + lane) * 8]); \
    al1 = *reinterpret_cast<const half8*>(&afrag[18432 + (((KT)*2 + 1) * 64 + lane) * 8]); \
  } while (0)

#define G1_ISSUE(B, P)                 \
  do {                                 \
    GLD16(R##B##0, voffA[2 * (P)]);    \
    GLD16O(R##B##1, voffA[2 * (P)]);   \
    GLD16(R##B##2, voffA[2 * (P) + 1]);  \
    GLD16O(R##B##3, voffA[2 * (P) + 1]); \
    voffA[2 * (P)] += 128;             \
    voffA[2 * (P) + 1] += 128;         \
  } while (0)

#define G1_FMA(B, P)                                            \
  do {                                                          \
    __builtin_amdgcn_s_setprio(1);                              \
    acc[0][2 * (P)] = MFMA16(ah0, asH8(R##B##0), acc[0][2 * (P)]); \
    acc[1][2 * (P)] = MFMA16(ah1, asH8(R##B##0), acc[1][2 * (P)]); \
    acc[0][2 * (P)] = MFMA16(ah0, asH8(R##B##1), acc[0][2 * (P)]); \
    acc[1][2 * (P)] = MFMA16(ah1, asH8(R##B##1), acc[1][2 * (P)]); \
    acc[0][2 * (P)] = MFMA16(al0, asH8(R##B##0), acc[0][2 * (P)]); \
    acc[1][2 * (P)] = MFMA16(al1, asH8(R##B##0), acc[1][2 * (P)]); \
    acc[0][2 * (P) + 1] = MFMA16(ah0, asH8(R##B##2), acc[0][2 * (P) + 1]); \
    acc[1][2 * (P) + 1] = MFMA16(ah1, asH8(R##B##2), acc[1][2 * (P) + 1]); \
    acc[0][2 * (P) + 1] = MFMA16(ah0, asH8(R##B##3), acc[0][2 * (P) + 1]); \
    acc[1][2 * (P) + 1] = MFMA16(ah1, asH8(R##B##3), acc[1][2 * (P) + 1]); \
    acc[0][2 * (P) + 1] = MFMA16(al0, asH8(R##B##2), acc[0][2 * (P) + 1]); \
    acc[1][2 * (P) + 1] = MFMA16(al1, asH8(R##B##2), acc[1][2 * (P) + 1]); \
    __builtin_amdgcn_s_setprio(0);                              \
  } while (0)

    G1_ISSUE(0, 0);
    G1_ISSUE(1, 1);
    G1_ISSUE(2, 2);
    for (int kt = 0; kt < 17; ++kt) {
      G1_AREAD(kt);
      G1_ISSUE(3, 3); VMW(12); G1_FMA(0, 0);
      G1_ISSUE(0, 0); VMW(12); G1_FMA(1, 1);
      G1_ISSUE(1, 1); VMW(12); G1_FMA(2, 2);
      G1_ISSUE(2, 2); VMW(12); G1_FMA(3, 3);
    }
    G1_AREAD(17);
    G1_ISSUE(3, 3); VMW(12); G1_FMA(0, 0);
    VMW(8); G1_FMA(1, 1);
    VMW(4); G1_FMA(2, 2);
    VMW(0); G1_FMA(3, 3);
  }

  // ---- softmax over m (512); lane: p = rt*16+koct*4+r, m = wv*128+mt*16+l15 ----
  float pm[2][4], ps[2][4], gm[2][4], rinv[2][4];
#pragma unroll
  for (int rt = 0; rt < 2; ++rt)
#pragma unroll
    for (int r = 0; r < 4; ++r) {
      float v = acc[rt][0][r];
#pragma unroll
      for (int mt = 1; mt < 8; ++mt) v = fmaxf(v, acc[rt][mt][r]);
      pm[rt][r] = v;
    }
#pragma unroll
  for (int off = 1; off < 16; off <<= 1)
#pragma unroll
    for (int rt = 0; rt < 2; ++rt)
#pragma unroll
      for (int r = 0; r < 4; ++r) pm[rt][r] = fmaxf(pm[rt][r], __shfl_xor(pm[rt][r], off, 64));
  if (l15 == 0) {
#pragma unroll
    for (int rt = 0; rt < 2; ++rt)
#pragma unroll
      for (int r = 0; r < 4; ++r) red_max[wv][rt * 16 + koct * 4 + r] = pm[rt][r];
  }
  __syncthreads();
#pragma unroll
  for (int rt = 0; rt < 2; ++rt)
#pragma unroll
    for (int r = 0; r < 4; ++r) {
      int p = rt * 16 + koct * 4 + r;
      gm[rt][r] = fmaxf(fmaxf(red_max[0][p], red_max[1][p]), fmaxf(red_max[2][p], red_max[3][p]));
      ps[rt][r] = 0.0f;
    }
#pragma unroll
  for (int rt = 0; rt < 2; ++rt)
#pragma unroll
    for (int mt = 0; mt < 8; ++mt)
#pragma unroll
      for (int r = 0; r < 4; ++r) {
        float e = exp2f((acc[rt][mt][r] - gm[rt][r]) * sfac);
        acc[rt][mt][r] = e;
        ps[rt][r] += e;
      }
#pragma unroll
  for (int off = 1; off < 16; off <<= 1)
#pragma unroll
    for (int rt = 0; rt < 2; ++rt)
#pragma unroll
      for (int r = 0; r < 4; ++r) ps[rt][r] += __shfl_xor(ps[rt][r], off, 64);
  if (l15 == 0) {
#pragma unroll
    for (int rt = 0; rt < 2; ++rt)
#pragma unroll
      for (int r = 0; r < 4; ++r) red_sum[wv][rt * 16 + koct * 4 + r] = ps[rt][r];
  }
  __syncthreads();
#pragma unroll
  for (int rt = 0; rt < 2; ++rt)
#pragma unroll
    for (int r = 0; r < 4; ++r) {
      int p = rt * 16 + koct * 4 + r;
      rinv[rt][r] = 1.0f / (red_sum[0][p] + red_sum[1][p] + red_sum[2][p] + red_sum[3][p]);
    }
  // write att-hi fragments into (aliased) afrag
#pragma unroll
  for (int rt = 0; rt < 2; ++rt)
#pragma unroll
    for (int mt = 0; mt < 8; ++mt)
#pragma unroll
      for (int r = 0; r < 4; ++r) {
        float a = acc[rt][mt][r] * rinv[rt][r];
        _Float16 hi = (_Float16)a;
        int m = wv * 128 + mt * 16 + l15;
        int lf = (koct * 4 + r) + (((m >> 3) & 3) << 4);
        int idxe = ((((m >> 5) << 1) + rt) * 64 + lf) * 8 + (m & 7);
        afrag[idxe] = hi;
      }
  __syncthreads();

  // ---- GEMM2 (single-term): out[32][576] = att_hi @ mem_hi; wave owns d in [wv*144,+144) ----
  floatx4 acc2[2][9];
#pragma unroll
  for (int rt = 0; rt < 2; ++rt)
#pragma unroll
    for (int nt = 0; nt < 9; ++nt) acc2[rt][nt] = zed;
  {
    const int d0 = wv * 144 + l15;
    int voffB[9];
#pragma unroll
    for (int nt = 0; nt < 9; ++nt) voffB[nt] = WS2 * 2 + (d0 + nt * 16) * 1024 + koct * 16;
    intx4 S00, S01, S02, S10, S11, S12, S20, S21, S22;
    half8 a2h0, a2h1;

#define G2_AREAD(KT)                                                                \
  do {                                                                              \
    a2h0 = *reinterpret_cast<const half8*>(&afrag[(((KT)*2 + 0) * 64 + lane) * 8]); \
    a2h1 = *reinterpret_cast<const half8*>(&afrag[(((KT)*2 + 1) * 64 + lane) * 8]); \
  } while (0)

#define G2_ISSUE(B, T)                \
  do {                                \
    GLD16(S##B##0, voffB[3 * (T)]);     \
    GLD16(S##B##1, voffB[3 * (T) + 1]); \
    GLD16(S##B##2, voffB[3 * (T) + 2]); \
    voffB[3 * (T)] += 64;             \
    voffB[3 * (T) + 1] += 64;         \
    voffB[3 * (T) + 2] += 64;         \
  } while (0)

#define G2_FMA(B, T)                                                        \
  do {                                                                      \
    __builtin_amdgcn_s_setprio(1);                                          \
    acc2[0][3 * (T)] = MFMA16(a2h0, asH8(S##B##0), acc2[0][3 * (T)]);       \
    acc2[1][3 * (T)] = MFMA16(a2h1, asH8(S##B##0), acc2[1][3 * (T)]);       \
    acc2[0][3 * (T) + 1] = MFMA16(a2h0, asH8(S##B##1), acc2[0][3 * (T) + 1]); \
    acc2[1][3 * (T) + 1] = MFMA16(a2h1, asH8(S##B##1), acc2[1][3 * (T) + 1]); \
    acc2[0][3 * (T) + 2] = MFMA16(a2h0, asH8(S##B##2), acc2[0][3 * (T) + 2]); \
    acc2[1][3 * (T) + 2] = MFMA16(a2h1, asH8(S##B##2), acc2[1][3 * (T) + 2]); \
    __builtin_amdgcn_s_setprio(0);                                          \
  } while (0)

    G2_ISSUE(0, 0);
    G2_ISSUE(1, 1);
    for (int kt2 = 0; kt2 < 15; ++kt2) {
      G2_AREAD(kt2);
      G2_ISSUE(2, 2); VMW(6); G2_FMA(0, 0);
      G2_ISSUE(0, 0); VMW(6); G2_FMA(1, 1);
      G2_ISSUE(1, 1); VMW(6); G2_FMA(2, 2);
    }
    G2_AREAD(15);
    G2_ISSUE(2, 2); VMW(6); G2_FMA(0, 0);
    VMW(3); G2_FMA(1, 1);
    VMW(0); G2_FMA(2, 2);
  }

  // ---- epilogue: nontemporal stores ----
  {
    const int nbase = b * 4096 + h * 64 + w0;
#pragma unroll
    for (int rt = 0; rt < 2; ++rt)
#pragma unroll
      for (int nt = 0; nt < 9; ++nt)
#pragma unroll
        for (int r = 0; r < 4; ++r) {
          int p = rt * 16 + koct * 4 + r;
          int d = wv * 144 + l15 + nt * 16;
          __builtin_nontemporal_store(acc2[rt][nt][r], &out[(nbase + p) * 576 + d]);
        }
  }
}

extern "C" void kernel_launch(void* const* d_in, const int* in_sizes, int n_in,
                              void* d_out, int out_size, void* d_ws, size_t ws_size,
                              hipStream_t stream) {
  const float* x = (const float*)d_in[0];
  const float* memory = (const float*)d_in[1];
  const float* temperature = (const float*)d_in[2];
  float* out = (float*)d_out;
  _Float16* ws = (_Float16*)d_ws;  // needs 1,769,472 bytes

  prep_split<<<512, 576, 0, stream>>>(memory, ws);
  mem_branch_kernel<<<2048, 256, 0, stream>>>(x, temperature, ws, out);
}